// Round 1
// baseline (773.014 us; speedup 1.0000x reference)
//
#include <hip/hip_runtime.h>
#include <math.h>

#define NN 50000
#define EE 640000
#define IND 23
#define HID 128
#define MIDD 64
#define NCLS 12

// ---- graph build ----------------------------------------------------------

__global__ void k_init(int* cnt, int n) {
    int i = blockIdx.x * blockDim.x + threadIdx.x;
    if (i < n) cnt[i] = 0;
}

__global__ void k_count(const int* __restrict__ dst, int* __restrict__ cnt, int e) {
    int i = blockIdx.x * blockDim.x + threadIdx.x;
    if (i < e) atomicAdd(&cnt[dst[i]], 1);
}

// single-block exclusive scan over cnt -> row_ptr; also dinv = 1/sqrt(cnt+1)
// and rewrites cnt[i] = row_ptr[i] so it can serve as the fill cursor.
__global__ void k_scan(int* __restrict__ cnt, int* __restrict__ row_ptr,
                       float* __restrict__ dinv, int n) {
    __shared__ int sdata[1024];
    __shared__ int s_run;
    int tid = threadIdx.x;
    if (tid == 0) s_run = 0;
    __syncthreads();
    for (int base = 0; base < n; base += 1024) {
        int i = base + tid;
        int v = (i < n) ? cnt[i] : 0;
        if (i < n) dinv[i] = 1.0f / sqrtf((float)v + 1.0f);  // +1 self loop
        sdata[tid] = v;
        __syncthreads();
        for (int off = 1; off < 1024; off <<= 1) {
            int t = (tid >= off) ? sdata[tid - off] : 0;
            __syncthreads();
            sdata[tid] += t;
            __syncthreads();
        }
        int run = s_run;
        int excl = run + sdata[tid] - v;
        if (i < n) { row_ptr[i] = excl; cnt[i] = excl; }
        int total = run + sdata[1023];
        __syncthreads();
        if (tid == 0) s_run = total;
        __syncthreads();
    }
    if (tid == 0) row_ptr[n] = s_run;
}

__global__ void k_fill(const int* __restrict__ src, const int* __restrict__ dst,
                       int* __restrict__ cursor, const float* __restrict__ dinv,
                       int* __restrict__ e_src, float* __restrict__ e_norm, int e) {
    int i = blockIdx.x * blockDim.x + threadIdx.x;
    if (i < e) {
        int s = src[i], d = dst[i];
        int pos = atomicAdd(&cursor[d], 1);
        e_src[pos] = s;
        e_norm[pos] = dinv[s] * dinv[d];
    }
}

// ---- dense layers ---------------------------------------------------------

// h[i,:] = x[i,:] @ W  (K=23).  block = node, thread = out column.
__global__ void k_lin_small(const float* __restrict__ x, const float* __restrict__ W,
                            float* __restrict__ out) {
    __shared__ float xs[IND];
    int i = blockIdx.x, c = threadIdx.x;
    if (c < IND) xs[c] = x[i * IND + c];
    __syncthreads();
    float acc = 0.f;
#pragma unroll
    for (int k = 0; k < IND; ++k) acc += xs[k] * W[k * HID + c];
    out[i * HID + c] = acc;
}

// h[i,:] = hin[i,:] @ W  (128x128).  block = node, thread = out column.
__global__ void k_lin128(const float* __restrict__ hin, const float* __restrict__ W,
                         float* __restrict__ out) {
    __shared__ float hs[HID];
    int i = blockIdx.x, c = threadIdx.x;
    hs[c] = hin[i * HID + c];
    __syncthreads();
    float acc = 0.f;
#pragma unroll 8
    for (int k = 0; k < HID; ++k) acc += hs[k] * W[k * HID + c];
    out[i * HID + c] = acc;
}

// out[i,:] = tanh( b + sum_{j in N(i)} hlin[src_j,:]*norm_j + hlin[i,:]*dinv[i]^2 )
__global__ void k_agg(const float* __restrict__ hlin, const float* __restrict__ b,
                      const int* __restrict__ row_ptr, const int* __restrict__ e_src,
                      const float* __restrict__ e_norm, const float* __restrict__ dinv,
                      float* __restrict__ out) {
    int i = blockIdx.x, f = threadIdx.x;
    float di = dinv[i];
    float acc = b[f] + hlin[i * HID + f] * di * di;   // self loop
    int beg = row_ptr[i], end = row_ptr[i + 1];
    for (int j = beg; j < end; ++j) {
        int s = e_src[j];
        float nrm = e_norm[j];
        acc += hlin[s * HID + f] * nrm;
    }
    out[i * HID + f] = tanhf(acc);
}

// classifier head: 128 -> 64 -> 12.  block = node, 64 threads.
__global__ void k_cls(const float* __restrict__ h, const float* __restrict__ Wc1,
                      const float* __restrict__ bc1, const float* __restrict__ Wc2,
                      const float* __restrict__ bc2, float* __restrict__ out) {
    __shared__ float hs[HID];
    __shared__ float ms[MIDD];
    int i = blockIdx.x, t = threadIdx.x;
    hs[t] = h[i * HID + t];
    hs[t + 64] = h[i * HID + t + 64];
    __syncthreads();
    float m = bc1[t];
#pragma unroll 8
    for (int k = 0; k < HID; ++k) m += hs[k] * Wc1[k * MIDD + t];
    ms[t] = m;
    __syncthreads();
    if (t < NCLS) {
        float o = bc2[t];
#pragma unroll
        for (int k = 0; k < MIDD; ++k) o += ms[k] * Wc2[k * NCLS + t];
        out[i * NCLS + t] = o;
    }
}

// ---- launch ---------------------------------------------------------------

extern "C" void kernel_launch(void* const* d_in, const int* in_sizes, int n_in,
                              void* d_out, int out_size, void* d_ws, size_t ws_size,
                              hipStream_t stream) {
    const float* x    = (const float*)d_in[0];
    const int*   edge = (const int*)d_in[1];
    const int*   src  = edge;
    const int*   dst  = edge + EE;
    const float* W1  = (const float*)d_in[2];  const float* b1  = (const float*)d_in[3];
    const float* W2  = (const float*)d_in[4];  const float* b2  = (const float*)d_in[5];
    const float* W3  = (const float*)d_in[6];  const float* b3  = (const float*)d_in[7];
    const float* Wc1 = (const float*)d_in[8];  const float* bc1 = (const float*)d_in[9];
    const float* Wc2 = (const float*)d_in[10]; const float* bc2 = (const float*)d_in[11];
    float* outp = (float*)d_out;

    char* p = (char*)d_ws;
    int*   cnt     = (int*)p;   p += (size_t)NN * 4;
    int*   row_ptr = (int*)p;   p += (size_t)(NN + 1) * 4;
    float* dinv    = (float*)p; p += (size_t)NN * 4;
    int*   e_src   = (int*)p;   p += (size_t)EE * 4;
    float* e_norm  = (float*)p; p += (size_t)EE * 4;
    float* hA      = (float*)p; p += (size_t)NN * HID * 4;
    float* hB      = (float*)p; p += (size_t)NN * HID * 4;

    // graph build
    k_init <<<(NN + 255) / 256, 256, 0, stream>>>(cnt, NN);
    k_count<<<(EE + 255) / 256, 256, 0, stream>>>(dst, cnt, EE);
    k_scan <<<1, 1024, 0, stream>>>(cnt, row_ptr, dinv, NN);
    k_fill <<<(EE + 255) / 256, 256, 0, stream>>>(src, dst, cnt, dinv, e_src, e_norm, EE);

    // layer 1
    k_lin_small<<<NN, HID, 0, stream>>>(x, W1, hA);
    k_agg      <<<NN, HID, 0, stream>>>(hA, b1, row_ptr, e_src, e_norm, dinv, hB);
    // layer 2
    k_lin128   <<<NN, HID, 0, stream>>>(hB, W2, hA);
    k_agg      <<<NN, HID, 0, stream>>>(hA, b2, row_ptr, e_src, e_norm, dinv, hB);
    // layer 3
    k_lin128   <<<NN, HID, 0, stream>>>(hB, W3, hA);
    k_agg      <<<NN, HID, 0, stream>>>(hA, b3, row_ptr, e_src, e_norm, dinv, hB);
    // head
    k_cls      <<<NN, MIDD, 0, stream>>>(hB, Wc1, bc1, Wc2, bc2, outp);
}

// Round 2
// 562.569 us; speedup vs baseline: 1.3741x; 1.3741x over previous
//
#include <hip/hip_runtime.h>
#include <math.h>

#define NN 50000
#define EE 640000
#define IND 23
#define HID 128
#define MIDD 64
#define NCLS 12

// ---- graph build ----------------------------------------------------------

__global__ void k_init(int* cnt, int n) {
    int i = blockIdx.x * blockDim.x + threadIdx.x;
    if (i < n) cnt[i] = 0;
}

__global__ void k_count(const int* __restrict__ dst, int* __restrict__ cnt, int e) {
    int i = blockIdx.x * blockDim.x + threadIdx.x;
    if (i < e) atomicAdd(&cnt[dst[i]], 1);
}

// single-block scan (shuffle-based, few barriers): cnt -> row_ptr (exclusive),
// dinv = rsqrt(cnt+1), cnt rewritten to row start (fill cursor).
__global__ void k_scan(int* __restrict__ cnt, int* __restrict__ row_ptr,
                       float* __restrict__ dinv, int n) {
    __shared__ int wsum[16];
    __shared__ int wexcl[16];
    __shared__ int tile_tot;
    __shared__ int s_run;
    const int tid = threadIdx.x;
    const int wid = tid >> 6;
    const int lane = tid & 63;
    if (tid == 0) s_run = 0;
    __syncthreads();
    for (int base = 0; base < n; base += 1024) {
        int i = base + tid;
        int v = (i < n) ? cnt[i] : 0;
        if (i < n) dinv[i] = rsqrtf((float)v + 1.0f);  // +1 self loop
        int val = v;
#pragma unroll
        for (int off = 1; off < 64; off <<= 1) {
            int t = __shfl_up(val, off, 64);
            if (lane >= off) val += t;
        }
        if (lane == 63) wsum[wid] = val;
        __syncthreads();
        if (wid == 0) {
            int t = (lane < 16) ? wsum[lane] : 0;
#pragma unroll
            for (int off = 1; off < 16; off <<= 1) {
                int u = __shfl_up(t, off, 16);
                if ((lane & 15) >= off) t += u;
            }
            if (lane < 16) wexcl[lane] = t - wsum[lane];
            if (lane == 15) tile_tot = t;
        }
        __syncthreads();
        int excl = s_run + wexcl[wid] + val - v;  // exclusive prefix
        if (i < n) { row_ptr[i] = excl; cnt[i] = excl; }
        __syncthreads();
        if (tid == 0) s_run += tile_tot;
        __syncthreads();
    }
    if (tid == 0) row_ptr[n] = s_run;
}

__global__ void k_fill(const int* __restrict__ src, const int* __restrict__ dst,
                       int* __restrict__ cursor, const float* __restrict__ dinv,
                       int* __restrict__ e_src, float* __restrict__ e_norm, int e) {
    int i = blockIdx.x * blockDim.x + threadIdx.x;
    if (i < e) {
        int s = src[i], d = dst[i];
        int pos = atomicAdd(&cursor[d], 1);
        e_src[pos] = s;
        e_norm[pos] = dinv[s] * dinv[d];
    }
}

// ---- layer 1: aggregate raw 23-dim features first (A@(XW) == (A@X)@W) -----

// xagg[i,:] = sum_{j in N(i)} x[src_j,:]*norm_j + x[i,:]*dinv[i]^2
// block = node, 256 threads = 8 edge-groups x 32 feature lanes (23 active)
__global__ void k_agg23(const float* __restrict__ x, const int* __restrict__ row_ptr,
                        const int* __restrict__ e_src, const float* __restrict__ e_norm,
                        const float* __restrict__ dinv, float* __restrict__ xagg) {
    __shared__ float part[256];
    const int i = blockIdx.x;
    const int tid = threadIdx.x;
    const int g = tid >> 5, lane = tid & 31;
    const int beg = row_ptr[i], end = row_ptr[i + 1];
    float acc = 0.f;
    for (int j = beg + g; j < end; j += 8) {
        int s = e_src[j];
        float nrm = e_norm[j];
        if (lane < IND) acc += x[s * IND + lane] * nrm;
    }
    part[tid] = acc;
    __syncthreads();
    if (tid < IND) {
        float di = dinv[i];
        float s = x[i * IND + tid] * di * di;
#pragma unroll
        for (int g2 = 0; g2 < 8; ++g2) s += part[g2 * 32 + tid];
        xagg[i * IND + tid] = s;
    }
}

// h1 = tanh(xagg @ W1 + b1).  8 nodes/block, 128 threads (one out column each).
__global__ void k_lin1(const float* __restrict__ xagg, const float* __restrict__ W1,
                       const float* __restrict__ b1, float* __restrict__ out) {
    __shared__ float xs[8 * IND];
    const int b0 = blockIdx.x * 8;
    const int c = threadIdx.x;
    for (int idx = c; idx < 8 * IND; idx += 128) {
        int gidx = b0 * IND + idx;
        xs[idx] = (gidx < NN * IND) ? xagg[gidx] : 0.f;
    }
    __syncthreads();
    float acc[8];
#pragma unroll
    for (int m = 0; m < 8; ++m) acc[m] = 0.f;
#pragma unroll
    for (int k = 0; k < IND; ++k) {
        float w = W1[k * HID + c];
#pragma unroll
        for (int m = 0; m < 8; ++m) acc[m] += xs[m * IND + k] * w;
    }
    float bb = b1[c];
#pragma unroll
    for (int m = 0; m < 8; ++m) {
        int node = b0 + m;
        if (node < NN) out[node * HID + c] = tanhf(acc[m] + bb);
    }
}

// ---- tiled 128x128 GEMM:  out[64x128 tile] = hin @ W  --------------------

__global__ __launch_bounds__(256) void k_gemm128(const float* __restrict__ hin,
                                                 const float* __restrict__ W,
                                                 float* __restrict__ out) {
    __shared__ float Hs[64 * 36];    // 64 rows x 32 k, padded to 36
    __shared__ float Ws[32 * 128];   // 32 k x 128 cols
    const int tid = threadIdx.x;
    const int b0 = blockIdx.x * 64;
    const int ng = tid >> 4;         // node group 0..15 (4 nodes each)
    const int cg = tid & 15;         // col group 0..15 (8 cols each)
    const float4* hin4 = (const float4*)hin;
    const float4* W4 = (const float4*)W;

    float acc[4][8];
#pragma unroll
    for (int m = 0; m < 4; ++m)
#pragma unroll
        for (int c = 0; c < 8; ++c) acc[m][c] = 0.f;

    for (int ks = 0; ks < HID; ks += 32) {
        // stage H tile: 64 rows x 32 k  (512 float4)
#pragma unroll
        for (int t = 0; t < 2; ++t) {
            int id = t * 256 + tid;
            int row = id >> 3;
            int k4 = id & 7;
            int node = b0 + row;
            float4 v = make_float4(0.f, 0.f, 0.f, 0.f);
            if (node < NN) v = hin4[node * 32 + (ks >> 2) + k4];
            *(float4*)&Hs[row * 36 + k4 * 4] = v;
        }
        // stage W tile: 32 k x 128 cols (1024 float4)
#pragma unroll
        for (int t = 0; t < 4; ++t) {
            int id = t * 256 + tid;
            int row = id >> 5;
            int c4 = id & 31;
            *(float4*)&Ws[row * 128 + c4 * 4] = W4[(ks + row) * 32 + c4];
        }
        __syncthreads();
#pragma unroll 8
        for (int kk = 0; kk < 32; ++kk) {
            float4 w0 = *(float4*)&Ws[kk * 128 + cg * 8];
            float4 w1 = *(float4*)&Ws[kk * 128 + cg * 8 + 4];
#pragma unroll
            for (int m = 0; m < 4; ++m) {
                float h = Hs[(ng * 4 + m) * 36 + kk];
                acc[m][0] += h * w0.x; acc[m][1] += h * w0.y;
                acc[m][2] += h * w0.z; acc[m][3] += h * w0.w;
                acc[m][4] += h * w1.x; acc[m][5] += h * w1.y;
                acc[m][6] += h * w1.z; acc[m][7] += h * w1.w;
            }
        }
        __syncthreads();
    }
    float4* out4 = (float4*)out;
#pragma unroll
    for (int m = 0; m < 4; ++m) {
        int node = b0 + ng * 4 + m;
        if (node < NN) {
            out4[node * 32 + cg * 2]     = make_float4(acc[m][0], acc[m][1], acc[m][2], acc[m][3]);
            out4[node * 32 + cg * 2 + 1] = make_float4(acc[m][4], acc[m][5], acc[m][6], acc[m][7]);
        }
    }
}

// ---- aggregation over 128-dim hidden: block=node, 8 edge-groups x 32 lanes
__global__ __launch_bounds__(256) void k_agg128(const float* __restrict__ hlin,
                                                const float* __restrict__ b,
                                                const int* __restrict__ row_ptr,
                                                const int* __restrict__ e_src,
                                                const float* __restrict__ e_norm,
                                                const float* __restrict__ dinv,
                                                float* __restrict__ out) {
    __shared__ float4 part[256];
    const int i = blockIdx.x;
    const int tid = threadIdx.x;
    const int g = tid >> 5, lane = tid & 31;
    const float4* h4 = (const float4*)hlin;
    const int beg = row_ptr[i], end = row_ptr[i + 1];
    float4 acc = make_float4(0.f, 0.f, 0.f, 0.f);
    for (int j = beg + g; j < end; j += 8) {
        int s = e_src[j];
        float nrm = e_norm[j];
        float4 v = h4[s * 32 + lane];
        acc.x += v.x * nrm; acc.y += v.y * nrm;
        acc.z += v.z * nrm; acc.w += v.w * nrm;
    }
    part[tid] = acc;
    __syncthreads();
    if (tid < 32) {
        float di = dinv[i];
        float sl = di * di;
        float4 v = h4[i * 32 + tid];
        float4 bb = ((const float4*)b)[tid];
        float4 s;
        s.x = bb.x + v.x * sl; s.y = bb.y + v.y * sl;
        s.z = bb.z + v.z * sl; s.w = bb.w + v.w * sl;
#pragma unroll
        for (int g2 = 0; g2 < 8; ++g2) {
            float4 p = part[g2 * 32 + tid];
            s.x += p.x; s.y += p.y; s.z += p.z; s.w += p.w;
        }
        s.x = tanhf(s.x); s.y = tanhf(s.y); s.z = tanhf(s.z); s.w = tanhf(s.w);
        ((float4*)out)[i * 32 + tid] = s;
    }
}

// ---- classifier head: 16 nodes/block, 128 -> 64 -> 12 ---------------------

__global__ __launch_bounds__(256) void k_cls(const float* __restrict__ h,
                                             const float* __restrict__ Wc1,
                                             const float* __restrict__ bc1,
                                             const float* __restrict__ Wc2,
                                             const float* __restrict__ bc2,
                                             float* __restrict__ out) {
    __shared__ float hs[16 * 128];   // 8 KB
    __shared__ float ms[16 * 65];    // mid activations, padded
    const int tid = threadIdx.x;
    const int b0 = blockIdx.x * 16;
    const float4* h4 = (const float4*)h;
    // load 16 node rows (512 float4)
#pragma unroll
    for (int t = 0; t < 2; ++t) {
        int id = t * 256 + tid;
        int node = id >> 5;
        int k4 = id & 31;
        float4 v = make_float4(0.f, 0.f, 0.f, 0.f);
        if (b0 + node < NN) v = h4[(b0 + node) * 32 + k4];
        *(float4*)&hs[node * 128 + k4 * 4] = v;
    }
    __syncthreads();
    // phase A: mid = h @ Wc1 + bc1   (thread: q=wave id -> 4 nodes, c = col)
    const int q = tid >> 6;          // 0..3
    const int c = tid & 63;
    float acc[4];
#pragma unroll
    for (int t = 0; t < 4; ++t) acc[t] = 0.f;
    for (int k = 0; k < HID; ++k) {
        float w = Wc1[k * MIDD + c];
#pragma unroll
        for (int t = 0; t < 4; ++t) acc[t] += hs[(q + 4 * t) * 128 + k] * w;
    }
    float bb = bc1[c];
#pragma unroll
    for (int t = 0; t < 4; ++t) ms[(q + 4 * t) * 65 + c] = acc[t] + bb;
    __syncthreads();
    // phase B: out = mid @ Wc2 + bc2
    if (tid < 16 * NCLS) {
        int m = tid / NCLS;
        int cls = tid % NCLS;
        int node = b0 + m;
        if (node < NN) {
            float o = bc2[cls];
#pragma unroll 8
            for (int k = 0; k < MIDD; ++k) o += ms[m * 65 + k] * Wc2[k * NCLS + cls];
            out[node * NCLS + cls] = o;
        }
    }
}

// ---- launch ---------------------------------------------------------------

extern "C" void kernel_launch(void* const* d_in, const int* in_sizes, int n_in,
                              void* d_out, int out_size, void* d_ws, size_t ws_size,
                              hipStream_t stream) {
    const float* x    = (const float*)d_in[0];
    const int*   edge = (const int*)d_in[1];
    const int*   src  = edge;
    const int*   dst  = edge + EE;
    const float* W1  = (const float*)d_in[2];  const float* b1  = (const float*)d_in[3];
    const float* W2  = (const float*)d_in[4];  const float* b2  = (const float*)d_in[5];
    const float* W3  = (const float*)d_in[6];  const float* b3  = (const float*)d_in[7];
    const float* Wc1 = (const float*)d_in[8];  const float* bc1 = (const float*)d_in[9];
    const float* Wc2 = (const float*)d_in[10]; const float* bc2 = (const float*)d_in[11];
    float* outp = (float*)d_out;

    char* p = (char*)d_ws;
    int*   cnt     = (int*)p;   p += (size_t)NN * 4;
    int*   row_ptr = (int*)p;   p += (size_t)(NN + 1) * 4 + 12;  // keep 16B align
    float* dinv    = (float*)p; p += (size_t)NN * 4;
    int*   e_src   = (int*)p;   p += (size_t)EE * 4;
    float* e_norm  = (float*)p; p += (size_t)EE * 4;
    float* hA      = (float*)p; p += (size_t)NN * HID * 4;
    float* hB      = (float*)p; p += (size_t)NN * HID * 4;
    float* xagg    = hB;   // alias: hB not live until k_gemm128 (layer 2)

    // graph build
    k_init <<<(NN + 255) / 256, 256, 0, stream>>>(cnt, NN);
    k_count<<<(EE + 255) / 256, 256, 0, stream>>>(dst, cnt, EE);
    k_scan <<<1, 1024, 0, stream>>>(cnt, row_ptr, dinv, NN);
    k_fill <<<(EE + 255) / 256, 256, 0, stream>>>(src, dst, cnt, dinv, e_src, e_norm, EE);

    // layer 1 (aggregate-first: (A@X)@W1)
    k_agg23<<<NN, 256, 0, stream>>>(x, row_ptr, e_src, e_norm, dinv, xagg);
    k_lin1 <<<(NN + 7) / 8, 128, 0, stream>>>(xagg, W1, b1, hA);
    // layer 2
    k_gemm128<<<(NN + 63) / 64, 256, 0, stream>>>(hA, W2, hB);
    k_agg128 <<<NN, 256, 0, stream>>>(hB, b2, row_ptr, e_src, e_norm, dinv, hA);
    // layer 3
    k_gemm128<<<(NN + 63) / 64, 256, 0, stream>>>(hA, W3, hB);
    k_agg128 <<<NN, 256, 0, stream>>>(hB, b3, row_ptr, e_src, e_norm, dinv, hA);
    // head
    k_cls<<<(NN + 15) / 16, 256, 0, stream>>>(hA, Wc1, bc1, Wc2, bc2, outp);
}

// Round 3
// 394.269 us; speedup vs baseline: 1.9606x; 1.4269x over previous
//
#include <hip/hip_runtime.h>
#include <math.h>

#define NN 50000
#define EE 640000
#define IND 23
#define HID 128
#define MIDD 64
#define NCLS 12
#define NB 49          // ceil(NN / 1024) scan chunks

// ---- graph build ----------------------------------------------------------

__global__ void k_count(const int* __restrict__ dst, int* __restrict__ cnt, int e) {
    int i = blockIdx.x * blockDim.x + threadIdx.x;
    if (i < e) atomicAdd(&cnt[dst[i]], 1);
}

// stage 1: per-block (1024-item) exclusive scan of cnt -> row_ptr (local),
// chunk totals -> sums, dinv = rsqrt(cnt+1).
__global__ __launch_bounds__(256) void k_scan_local(const int* __restrict__ cnt,
                                                    int* __restrict__ row_ptr,
                                                    float* __restrict__ dinv,
                                                    int* __restrict__ sums) {
    __shared__ int wtot[4];
    const int tid = threadIdx.x;
    const int wid = tid >> 6, lane = tid & 63;
    const int base = blockIdx.x * 1024 + tid * 4;
    int v[4];
#pragma unroll
    for (int t = 0; t < 4; ++t) {
        int i = base + t;
        v[t] = (i < NN) ? cnt[i] : 0;
        if (i < NN) dinv[i] = rsqrtf((float)v[t] + 1.0f);  // +1 self loop
    }
    int slocal = v[0] + v[1] + v[2] + v[3];
    int val = slocal;
#pragma unroll
    for (int off = 1; off < 64; off <<= 1) {
        int t = __shfl_up(val, off, 64);
        if (lane >= off) val += t;
    }
    if (lane == 63) wtot[wid] = val;
    __syncthreads();
    int woff = 0;
#pragma unroll
    for (int w = 0; w < 4; ++w) woff += (w < wid) ? wtot[w] : 0;
    int run = woff + val - slocal;  // exclusive prefix of this thread's group
#pragma unroll
    for (int t = 0; t < 4; ++t) {
        int i = base + t;
        if (i < NN) row_ptr[i] = run;
        run += v[t];
    }
    if (tid == 255) sums[blockIdx.x] = woff + val;  // block total
}

// stage 2: scan the NB chunk sums -> offs (exclusive); total -> row_ptr[NN].
__global__ void k_scan_sums(const int* __restrict__ sums, int* __restrict__ offs,
                            int* __restrict__ row_ptr) {
    const int lane = threadIdx.x;
    int v = (lane < NB) ? sums[lane] : 0;
    int val = v;
#pragma unroll
    for (int off = 1; off < 64; off <<= 1) {
        int t = __shfl_up(val, off, 64);
        if (lane >= off) val += t;
    }
    if (lane < NB) offs[lane] = val - v;
    if (lane == NB - 1) row_ptr[NN] = val;
}

// stage 3: add chunk offsets; cursor (=cnt reused) gets row starts for fill.
__global__ __launch_bounds__(256) void k_scan_apply(int* __restrict__ row_ptr,
                                                    const int* __restrict__ offs,
                                                    int* __restrict__ cursor) {
    const int base = blockIdx.x * 1024 + threadIdx.x * 4;
    const int o = offs[blockIdx.x];
#pragma unroll
    for (int t = 0; t < 4; ++t) {
        int i = base + t;
        if (i < NN) {
            int rp = row_ptr[i] + o;
            row_ptr[i] = rp;
            cursor[i] = rp;
        }
    }
}

__global__ void k_fill(const int* __restrict__ src, const int* __restrict__ dst,
                       int* __restrict__ cursor, int* __restrict__ e_src, int e) {
    int i = blockIdx.x * blockDim.x + threadIdx.x;
    if (i < e) {
        int d = dst[i];
        int pos = atomicAdd(&cursor[d], 1);
        e_src[pos] = src[i];
    }
}

// ---- layer 1 fused: h1 = tanh( (A @ x) @ W1 + b1 ) ------------------------
// wave per node; 4 nodes/block. Phase 1: aggregate 23-dim x into registers
// (2 edges per wave-iteration, half-wave each). Phase 2: broadcast via shfl,
// each lane computes output cols {lane, lane+64}.
__global__ __launch_bounds__(256) void k_l1(const float* __restrict__ x,
                                            const float* __restrict__ W1,
                                            const float* __restrict__ b1,
                                            const int* __restrict__ row_ptr,
                                            const int* __restrict__ e_src,
                                            const float* __restrict__ dinv,
                                            float* __restrict__ out) {
    const int tid = threadIdx.x;
    const int i = blockIdx.x * 4 + (tid >> 6);
    const int lane = tid & 63;
    const int h = lane >> 5;        // edge slot 0/1
    const int f = lane & 31;        // feature lane (active if < 23)
    const float di = dinv[i];
    const int beg = row_ptr[i], end = row_ptr[i + 1];
    float acc = 0.f;
    for (int j = beg + h; j < end; j += 2) {
        int s = e_src[j];
        float nrm = dinv[s] * di;
        if (f < IND) acc += x[s * IND + f] * nrm;
    }
    acc += __shfl_down(acc, 32, 64);               // fold slot 1 into slot 0
    if (lane < IND) acc += x[i * IND + lane] * di * di;  // self loop
    // phase 2: every lane needs xagg[0..22] -> broadcast from lanes 0..22
    float a0 = b1[lane], a1 = b1[lane + 64];
#pragma unroll
    for (int k = 0; k < IND; ++k) {
        float xk = __shfl(acc, k, 64);
        a0 += xk * W1[k * HID + lane];
        a1 += xk * W1[k * HID + lane + 64];
    }
    out[i * HID + lane]      = tanhf(a0);
    out[i * HID + lane + 64] = tanhf(a1);
}

// ---- tiled 128x128 GEMM:  out[64x128 tile] = hin @ W ----------------------

__global__ __launch_bounds__(256) void k_gemm128(const float* __restrict__ hin,
                                                 const float* __restrict__ W,
                                                 float* __restrict__ out) {
    __shared__ float Hs[64 * 36];
    __shared__ float Ws[32 * 128];
    const int tid = threadIdx.x;
    const int b0 = blockIdx.x * 64;
    const int ng = tid >> 4;
    const int cg = tid & 15;
    const float4* hin4 = (const float4*)hin;
    const float4* W4 = (const float4*)W;

    float acc[4][8];
#pragma unroll
    for (int m = 0; m < 4; ++m)
#pragma unroll
        for (int c = 0; c < 8; ++c) acc[m][c] = 0.f;

    for (int ks = 0; ks < HID; ks += 32) {
#pragma unroll
        for (int t = 0; t < 2; ++t) {
            int id = t * 256 + tid;
            int row = id >> 3;
            int k4 = id & 7;
            int node = b0 + row;
            float4 v = make_float4(0.f, 0.f, 0.f, 0.f);
            if (node < NN) v = hin4[node * 32 + (ks >> 2) + k4];
            *(float4*)&Hs[row * 36 + k4 * 4] = v;
        }
#pragma unroll
        for (int t = 0; t < 4; ++t) {
            int id = t * 256 + tid;
            int row = id >> 5;
            int c4 = id & 31;
            *(float4*)&Ws[row * 128 + c4 * 4] = W4[(ks + row) * 32 + c4];
        }
        __syncthreads();
#pragma unroll 8
        for (int kk = 0; kk < 32; ++kk) {
            float4 w0 = *(float4*)&Ws[kk * 128 + cg * 8];
            float4 w1 = *(float4*)&Ws[kk * 128 + cg * 8 + 4];
#pragma unroll
            for (int m = 0; m < 4; ++m) {
                float hv = Hs[(ng * 4 + m) * 36 + kk];
                acc[m][0] += hv * w0.x; acc[m][1] += hv * w0.y;
                acc[m][2] += hv * w0.z; acc[m][3] += hv * w0.w;
                acc[m][4] += hv * w1.x; acc[m][5] += hv * w1.y;
                acc[m][6] += hv * w1.z; acc[m][7] += hv * w1.w;
            }
        }
        __syncthreads();
    }
    float4* out4 = (float4*)out;
#pragma unroll
    for (int m = 0; m < 4; ++m) {
        int node = b0 + ng * 4 + m;
        if (node < NN) {
            out4[node * 32 + cg * 2]     = make_float4(acc[m][0], acc[m][1], acc[m][2], acc[m][3]);
            out4[node * 32 + cg * 2 + 1] = make_float4(acc[m][4], acc[m][5], acc[m][6], acc[m][7]);
        }
    }
}

// ---- 128-dim aggregation: wave per node, 2 edges/iter, shuffle reduce -----

__global__ __launch_bounds__(256) void k_agg128(const float* __restrict__ hlin,
                                                const float* __restrict__ b,
                                                const int* __restrict__ row_ptr,
                                                const int* __restrict__ e_src,
                                                const float* __restrict__ dinv,
                                                float* __restrict__ out) {
    const int tid = threadIdx.x;
    const int i = blockIdx.x * 4 + (tid >> 6);
    const int lane = tid & 63;
    const int h = lane >> 5;        // edge slot
    const int f4 = lane & 31;       // float4 index within row
    const float4* h4 = (const float4*)hlin;
    const float di = dinv[i];
    const int beg = row_ptr[i], end = row_ptr[i + 1];
    float4 acc = make_float4(0.f, 0.f, 0.f, 0.f);
    for (int j = beg + h; j < end; j += 2) {
        int s = e_src[j];
        float nrm = dinv[s] * di;
        float4 v = h4[s * 32 + f4];
        acc.x += v.x * nrm; acc.y += v.y * nrm;
        acc.z += v.z * nrm; acc.w += v.w * nrm;
    }
    acc.x += __shfl_down(acc.x, 32, 64);
    acc.y += __shfl_down(acc.y, 32, 64);
    acc.z += __shfl_down(acc.z, 32, 64);
    acc.w += __shfl_down(acc.w, 32, 64);
    if (lane < 32) {
        float sl = di * di;
        float4 v = h4[i * 32 + lane];
        float4 bb = ((const float4*)b)[lane];
        float4 s;
        s.x = tanhf(bb.x + acc.x + v.x * sl);
        s.y = tanhf(bb.y + acc.y + v.y * sl);
        s.z = tanhf(bb.z + acc.z + v.z * sl);
        s.w = tanhf(bb.w + acc.w + v.w * sl);
        ((float4*)out)[i * 32 + lane] = s;
    }
}

// ---- classifier head: 16 nodes/block, 128 -> 64 -> 12 ---------------------

__global__ __launch_bounds__(256) void k_cls(const float* __restrict__ h,
                                             const float* __restrict__ Wc1,
                                             const float* __restrict__ bc1,
                                             const float* __restrict__ Wc2,
                                             const float* __restrict__ bc2,
                                             float* __restrict__ out) {
    __shared__ float hs[16 * 128];
    __shared__ float ms[16 * 65];
    const int tid = threadIdx.x;
    const int b0 = blockIdx.x * 16;
    const float4* h4 = (const float4*)h;
#pragma unroll
    for (int t = 0; t < 2; ++t) {
        int id = t * 256 + tid;
        int node = id >> 5;
        int k4 = id & 31;
        float4 v = make_float4(0.f, 0.f, 0.f, 0.f);
        if (b0 + node < NN) v = h4[(b0 + node) * 32 + k4];
        *(float4*)&hs[node * 128 + k4 * 4] = v;
    }
    __syncthreads();
    const int q = tid >> 6;
    const int c = tid & 63;
    float acc[4];
#pragma unroll
    for (int t = 0; t < 4; ++t) acc[t] = 0.f;
    for (int k = 0; k < HID; ++k) {
        float w = Wc1[k * MIDD + c];
#pragma unroll
        for (int t = 0; t < 4; ++t) acc[t] += hs[(q + 4 * t) * 128 + k] * w;
    }
    float bb = bc1[c];
#pragma unroll
    for (int t = 0; t < 4; ++t) ms[(q + 4 * t) * 65 + c] = acc[t] + bb;
    __syncthreads();
    if (tid < 16 * NCLS) {
        int m = tid / NCLS;
        int cls = tid % NCLS;
        int node = b0 + m;
        if (node < NN) {
            float o = bc2[cls];
#pragma unroll 8
            for (int k = 0; k < MIDD; ++k) o += ms[m * 65 + k] * Wc2[k * NCLS + cls];
            out[node * NCLS + cls] = o;
        }
    }
}

// ---- launch ---------------------------------------------------------------

extern "C" void kernel_launch(void* const* d_in, const int* in_sizes, int n_in,
                              void* d_out, int out_size, void* d_ws, size_t ws_size,
                              hipStream_t stream) {
    const float* x    = (const float*)d_in[0];
    const int*   edge = (const int*)d_in[1];
    const int*   src  = edge;
    const int*   dst  = edge + EE;
    const float* W1  = (const float*)d_in[2];  const float* b1  = (const float*)d_in[3];
    const float* W2  = (const float*)d_in[4];  const float* b2  = (const float*)d_in[5];
    const float* W3  = (const float*)d_in[6];  const float* b3  = (const float*)d_in[7];
    const float* Wc1 = (const float*)d_in[8];  const float* bc1 = (const float*)d_in[9];
    const float* Wc2 = (const float*)d_in[10]; const float* bc2 = (const float*)d_in[11];
    float* outp = (float*)d_out;

    char* p = (char*)d_ws;
    int*   cnt     = (int*)p;   p += 200064;          // NN ints, padded
    int*   row_ptr = (int*)p;   p += 200064;          // NN+1 ints, padded
    float* dinv    = (float*)p; p += 200064;
    int*   sums    = (int*)p;   p += 256;
    int*   offs    = (int*)p;   p += 256;
    int*   e_src   = (int*)p;   p += (size_t)EE * 4;
    float* hA      = (float*)p; p += (size_t)NN * HID * 4;
    float* hB      = (float*)p; p += (size_t)NN * HID * 4;

    // graph build
    hipMemsetAsync(cnt, 0, (size_t)NN * 4, stream);
    k_count     <<<(EE + 255) / 256, 256, 0, stream>>>(dst, cnt, EE);
    k_scan_local<<<NB, 256, 0, stream>>>(cnt, row_ptr, dinv, sums);
    k_scan_sums <<<1, 64, 0, stream>>>(sums, offs, row_ptr);
    k_scan_apply<<<NB, 256, 0, stream>>>(row_ptr, offs, cnt);   // cnt becomes cursor
    k_fill      <<<(EE + 255) / 256, 256, 0, stream>>>(src, dst, cnt, e_src, EE);

    // layer 1 (fused (A@X)@W1)
    k_l1     <<<NN / 4, 256, 0, stream>>>(x, W1, b1, row_ptr, e_src, dinv, hA);
    // layer 2
    k_gemm128<<<(NN + 63) / 64, 256, 0, stream>>>(hA, W2, hB);
    k_agg128 <<<NN / 4, 256, 0, stream>>>(hB, b2, row_ptr, e_src, dinv, hA);
    // layer 3
    k_gemm128<<<(NN + 63) / 64, 256, 0, stream>>>(hA, W3, hB);
    k_agg128 <<<NN / 4, 256, 0, stream>>>(hB, b3, row_ptr, e_src, dinv, hA);
    // head
    k_cls<<<(NN + 15) / 16, 256, 0, stream>>>(hA, Wc1, bc1, Wc2, bc2, outp);
}

// Round 4
// 383.228 us; speedup vs baseline: 2.0171x; 1.0288x over previous
//
#include <hip/hip_runtime.h>
#include <math.h>

#define NN 50000
#define EE 640000
#define IND 23
#define HID 128
#define MIDD 64
#define NCLS 12
#define NB 49          // ceil(NN / 1024) scan chunks

// ---- graph build ----------------------------------------------------------

__global__ void k_count(const int* __restrict__ dst, int* __restrict__ cnt, int e) {
    int i = blockIdx.x * blockDim.x + threadIdx.x;
    if (i < e) atomicAdd(&cnt[dst[i]], 1);
}

__global__ __launch_bounds__(256) void k_scan_local(const int* __restrict__ cnt,
                                                    int* __restrict__ row_ptr,
                                                    float* __restrict__ dinv,
                                                    int* __restrict__ sums) {
    __shared__ int wtot[4];
    const int tid = threadIdx.x;
    const int wid = tid >> 6, lane = tid & 63;
    const int base = blockIdx.x * 1024 + tid * 4;
    int v[4];
#pragma unroll
    for (int t = 0; t < 4; ++t) {
        int i = base + t;
        v[t] = (i < NN) ? cnt[i] : 0;
        if (i < NN) dinv[i] = rsqrtf((float)v[t] + 1.0f);  // +1 self loop
    }
    int slocal = v[0] + v[1] + v[2] + v[3];
    int val = slocal;
#pragma unroll
    for (int off = 1; off < 64; off <<= 1) {
        int t = __shfl_up(val, off, 64);
        if (lane >= off) val += t;
    }
    if (lane == 63) wtot[wid] = val;
    __syncthreads();
    int woff = 0;
#pragma unroll
    for (int w = 0; w < 4; ++w) woff += (w < wid) ? wtot[w] : 0;
    int run = woff + val - slocal;
#pragma unroll
    for (int t = 0; t < 4; ++t) {
        int i = base + t;
        if (i < NN) row_ptr[i] = run;
        run += v[t];
    }
    if (tid == 255) sums[blockIdx.x] = woff + val;
}

__global__ void k_scan_sums(const int* __restrict__ sums, int* __restrict__ offs,
                            int* __restrict__ row_ptr) {
    const int lane = threadIdx.x;
    int v = (lane < NB) ? sums[lane] : 0;
    int val = v;
#pragma unroll
    for (int off = 1; off < 64; off <<= 1) {
        int t = __shfl_up(val, off, 64);
        if (lane >= off) val += t;
    }
    if (lane < NB) offs[lane] = val - v;
    if (lane == NB - 1) row_ptr[NN] = val;
}

__global__ __launch_bounds__(256) void k_scan_apply(int* __restrict__ row_ptr,
                                                    const int* __restrict__ offs,
                                                    int* __restrict__ cursor) {
    const int base = blockIdx.x * 1024 + threadIdx.x * 4;
    const int o = offs[blockIdx.x];
#pragma unroll
    for (int t = 0; t < 4; ++t) {
        int i = base + t;
        if (i < NN) {
            int rp = row_ptr[i] + o;
            row_ptr[i] = rp;
            cursor[i] = rp;
        }
    }
}

__global__ void k_fill(const int* __restrict__ src, const int* __restrict__ dst,
                       int* __restrict__ cursor, int* __restrict__ e_src, int e) {
    int i = blockIdx.x * blockDim.x + threadIdx.x;
    if (i < e) {
        int d = dst[i];
        int pos = atomicAdd(&cursor[d], 1);
        e_src[pos] = src[i];
    }
}

// pad x rows 23 -> 32 floats (aligned 128B rows, zero-filled tail)
__global__ __launch_bounds__(256) void k_pad(const float* __restrict__ x,
                                             float* __restrict__ xp) {
    int i = blockIdx.x * 256 + threadIdx.x;   // over NN*32
    int node = i >> 5, f = i & 31;
    xp[i] = (f < IND) ? x[node * IND + f] : 0.f;
}

// ---- layer 1 fused: h1 = tanh( (A @ x) @ W1 + b1 ) ------------------------
// wave per node. Segment-batched gather: whole edge segment's src+norm loaded
// into registers first (one coalesced load + parallel dinv gathers), then the
// x-row gather loop runs off shfl broadcasts (no serial pointer chain).
__global__ __launch_bounds__(256) void k_l1(const float* __restrict__ xp,
                                            const float* __restrict__ W1,
                                            const float* __restrict__ b1,
                                            const int* __restrict__ row_ptr,
                                            const int* __restrict__ e_src,
                                            const float* __restrict__ dinv,
                                            float* __restrict__ out) {
    const int tid = threadIdx.x;
    const int i = blockIdx.x * 4 + (tid >> 6);
    const int lane = tid & 63;
    const int slot = lane >> 5;     // edge slot 0/1
    const int f = lane & 31;        // feature lane (23 live, 9 padded zeros)
    const float di = dinv[i];
    const int beg = row_ptr[i];
    const int deg = row_ptr[i + 1] - beg;
    float acc = 0.f;
    for (int base = 0; base < deg; base += 64) {
        const int cnt = min(64, deg - base);
        int s_l = 0; float nrm_l = 0.f;
        if (lane < cnt) {
            s_l = e_src[beg + base + lane];
            nrm_l = dinv[s_l] * di;
        }
        int e = 0;
#pragma unroll 4
        for (; e + 1 < cnt; e += 2) {
            int s = __shfl(s_l, e + slot, 64);
            float nrm = __shfl(nrm_l, e + slot, 64);
            acc += xp[s * 32 + f] * nrm;
        }
        if (e < cnt) {
            int s = __shfl(s_l, e, 64);
            float nrm = __shfl(nrm_l, e, 64);
            if (slot == 0) acc += xp[s * 32 + f] * nrm;
        }
    }
    acc += __shfl_down(acc, 32, 64);                 // fold slot 1 -> lanes 0..31
    if (lane < 32) acc += xp[i * 32 + lane] * di * di;  // self loop
    // phase 2: broadcast xagg[0..22] from lanes 0..22
    float a0 = b1[lane], a1 = b1[lane + 64];
#pragma unroll
    for (int k = 0; k < IND; ++k) {
        float xk = __shfl(acc, k, 64);
        a0 += xk * W1[k * HID + lane];
        a1 += xk * W1[k * HID + lane + 64];
    }
    out[i * HID + lane]      = tanhf(a0);
    out[i * HID + lane + 64] = tanhf(a1);
}

// ---- tiled 128x128 GEMM:  out[64x128 tile] = hin @ W ----------------------

__global__ __launch_bounds__(256) void k_gemm128(const float* __restrict__ hin,
                                                 const float* __restrict__ W,
                                                 float* __restrict__ out) {
    __shared__ float Hs[64 * 36];
    __shared__ float Ws[32 * 128];
    const int tid = threadIdx.x;
    const int b0 = blockIdx.x * 64;
    const int ng = tid >> 4;
    const int cg = tid & 15;
    const float4* hin4 = (const float4*)hin;
    const float4* W4 = (const float4*)W;

    float acc[4][8];
#pragma unroll
    for (int m = 0; m < 4; ++m)
#pragma unroll
        for (int c = 0; c < 8; ++c) acc[m][c] = 0.f;

    for (int ks = 0; ks < HID; ks += 32) {
#pragma unroll
        for (int t = 0; t < 2; ++t) {
            int id = t * 256 + tid;
            int row = id >> 3;
            int k4 = id & 7;
            int node = b0 + row;
            float4 v = make_float4(0.f, 0.f, 0.f, 0.f);
            if (node < NN) v = hin4[node * 32 + (ks >> 2) + k4];
            *(float4*)&Hs[row * 36 + k4 * 4] = v;
        }
#pragma unroll
        for (int t = 0; t < 4; ++t) {
            int id = t * 256 + tid;
            int row = id >> 5;
            int c4 = id & 31;
            *(float4*)&Ws[row * 128 + c4 * 4] = W4[(ks + row) * 32 + c4];
        }
        __syncthreads();
#pragma unroll 8
        for (int kk = 0; kk < 32; ++kk) {
            float4 w0 = *(float4*)&Ws[kk * 128 + cg * 8];
            float4 w1 = *(float4*)&Ws[kk * 128 + cg * 8 + 4];
#pragma unroll
            for (int m = 0; m < 4; ++m) {
                float hv = Hs[(ng * 4 + m) * 36 + kk];
                acc[m][0] += hv * w0.x; acc[m][1] += hv * w0.y;
                acc[m][2] += hv * w0.z; acc[m][3] += hv * w0.w;
                acc[m][4] += hv * w1.x; acc[m][5] += hv * w1.y;
                acc[m][6] += hv * w1.z; acc[m][7] += hv * w1.w;
            }
        }
        __syncthreads();
    }
    float4* out4 = (float4*)out;
#pragma unroll
    for (int m = 0; m < 4; ++m) {
        int node = b0 + ng * 4 + m;
        if (node < NN) {
            out4[node * 32 + cg * 2]     = make_float4(acc[m][0], acc[m][1], acc[m][2], acc[m][3]);
            out4[node * 32 + cg * 2 + 1] = make_float4(acc[m][4], acc[m][5], acc[m][6], acc[m][7]);
        }
    }
}

// ---- 128-dim aggregation: wave per node, segment-batched gather -----------

__global__ __launch_bounds__(256) void k_agg128(const float* __restrict__ hlin,
                                                const float* __restrict__ b,
                                                const int* __restrict__ row_ptr,
                                                const int* __restrict__ e_src,
                                                const float* __restrict__ dinv,
                                                float* __restrict__ out) {
    const int tid = threadIdx.x;
    const int i = blockIdx.x * 4 + (tid >> 6);
    const int lane = tid & 63;
    const int slot = lane >> 5;
    const int f4 = lane & 31;
    const float4* h4 = (const float4*)hlin;
    const float di = dinv[i];
    const int beg = row_ptr[i];
    const int deg = row_ptr[i + 1] - beg;
    float4 acc = make_float4(0.f, 0.f, 0.f, 0.f);
    for (int base = 0; base < deg; base += 64) {
        const int cnt = min(64, deg - base);
        int s_l = 0; float nrm_l = 0.f;
        if (lane < cnt) {
            s_l = e_src[beg + base + lane];
            nrm_l = dinv[s_l] * di;
        }
        int e = 0;
#pragma unroll 4
        for (; e + 1 < cnt; e += 2) {
            int s = __shfl(s_l, e + slot, 64);
            float nrm = __shfl(nrm_l, e + slot, 64);
            float4 v = h4[s * 32 + f4];
            acc.x += v.x * nrm; acc.y += v.y * nrm;
            acc.z += v.z * nrm; acc.w += v.w * nrm;
        }
        if (e < cnt) {
            int s = __shfl(s_l, e, 64);
            float nrm = __shfl(nrm_l, e, 64);
            if (slot == 0) {
                float4 v = h4[s * 32 + f4];
                acc.x += v.x * nrm; acc.y += v.y * nrm;
                acc.z += v.z * nrm; acc.w += v.w * nrm;
            }
        }
    }
    acc.x += __shfl_down(acc.x, 32, 64);
    acc.y += __shfl_down(acc.y, 32, 64);
    acc.z += __shfl_down(acc.z, 32, 64);
    acc.w += __shfl_down(acc.w, 32, 64);
    if (lane < 32) {
        float sl = di * di;
        float4 v = h4[i * 32 + lane];
        float4 bb = ((const float4*)b)[lane];
        float4 s;
        s.x = tanhf(bb.x + acc.x + v.x * sl);
        s.y = tanhf(bb.y + acc.y + v.y * sl);
        s.z = tanhf(bb.z + acc.z + v.z * sl);
        s.w = tanhf(bb.w + acc.w + v.w * sl);
        ((float4*)out)[i * 32 + lane] = s;
    }
}

// ---- classifier head: 16 nodes/block, 128 -> 64 -> 12 ---------------------

__global__ __launch_bounds__(256) void k_cls(const float* __restrict__ h,
                                             const float* __restrict__ Wc1,
                                             const float* __restrict__ bc1,
                                             const float* __restrict__ Wc2,
                                             const float* __restrict__ bc2,
                                             float* __restrict__ out) {
    __shared__ float hs[16 * 128];
    __shared__ float ms[16 * 65];
    const int tid = threadIdx.x;
    const int b0 = blockIdx.x * 16;
    const float4* h4 = (const float4*)h;
#pragma unroll
    for (int t = 0; t < 2; ++t) {
        int id = t * 256 + tid;
        int node = id >> 5;
        int k4 = id & 31;
        float4 v = make_float4(0.f, 0.f, 0.f, 0.f);
        if (b0 + node < NN) v = h4[(b0 + node) * 32 + k4];
        *(float4*)&hs[node * 128 + k4 * 4] = v;
    }
    __syncthreads();
    const int q = tid >> 6;
    const int c = tid & 63;
    float acc[4];
#pragma unroll
    for (int t = 0; t < 4; ++t) acc[t] = 0.f;
    for (int k = 0; k < HID; ++k) {
        float w = Wc1[k * MIDD + c];
#pragma unroll
        for (int t = 0; t < 4; ++t) acc[t] += hs[(q + 4 * t) * 128 + k] * w;
    }
    float bb = bc1[c];
#pragma unroll
    for (int t = 0; t < 4; ++t) ms[(q + 4 * t) * 65 + c] = acc[t] + bb;
    __syncthreads();
    if (tid < 16 * NCLS) {
        int m = tid / NCLS;
        int cls = tid % NCLS;
        int node = b0 + m;
        if (node < NN) {
            float o = bc2[cls];
#pragma unroll 8
            for (int k = 0; k < MIDD; ++k) o += ms[m * 65 + k] * Wc2[k * NCLS + cls];
            out[node * NCLS + cls] = o;
        }
    }
}

// ---- launch ---------------------------------------------------------------

extern "C" void kernel_launch(void* const* d_in, const int* in_sizes, int n_in,
                              void* d_out, int out_size, void* d_ws, size_t ws_size,
                              hipStream_t stream) {
    const float* x    = (const float*)d_in[0];
    const int*   edge = (const int*)d_in[1];
    const int*   src  = edge;
    const int*   dst  = edge + EE;
    const float* W1  = (const float*)d_in[2];  const float* b1  = (const float*)d_in[3];
    const float* W2  = (const float*)d_in[4];  const float* b2  = (const float*)d_in[5];
    const float* W3  = (const float*)d_in[6];  const float* b3  = (const float*)d_in[7];
    const float* Wc1 = (const float*)d_in[8];  const float* bc1 = (const float*)d_in[9];
    const float* Wc2 = (const float*)d_in[10]; const float* bc2 = (const float*)d_in[11];
    float* outp = (float*)d_out;

    char* p = (char*)d_ws;
    int*   cnt     = (int*)p;   p += 200064;          // NN ints, padded
    int*   row_ptr = (int*)p;   p += 200064;          // NN+1 ints, padded
    float* dinv    = (float*)p; p += 200064;
    int*   sums    = (int*)p;   p += 256;
    int*   offs    = (int*)p;   p += 256;
    int*   e_src   = (int*)p;   p += (size_t)EE * 4;
    float* hA      = (float*)p; p += (size_t)NN * HID * 4;
    float* hB      = (float*)p; p += (size_t)NN * HID * 4;
    float* xp      = hB;   // alias: hB not live until layer-2 gemm; xp dead by then

    // graph build
    hipMemsetAsync(cnt, 0, (size_t)NN * 4, stream);
    k_count     <<<(EE + 255) / 256, 256, 0, stream>>>(dst, cnt, EE);
    k_scan_local<<<NB, 256, 0, stream>>>(cnt, row_ptr, dinv, sums);
    k_scan_sums <<<1, 64, 0, stream>>>(sums, offs, row_ptr);
    k_scan_apply<<<NB, 256, 0, stream>>>(row_ptr, offs, cnt);   // cnt becomes cursor
    k_fill      <<<(EE + 255) / 256, 256, 0, stream>>>(src, dst, cnt, e_src, EE);
    k_pad       <<<(NN * 32) / 256, 256, 0, stream>>>(x, xp);

    // layer 1 (fused (A@X)@W1)
    k_l1     <<<NN / 4, 256, 0, stream>>>(xp, W1, b1, row_ptr, e_src, dinv, hA);
    // layer 2
    k_gemm128<<<(NN + 63) / 64, 256, 0, stream>>>(hA, W2, hB);
    k_agg128 <<<NN / 4, 256, 0, stream>>>(hB, b2, row_ptr, e_src, dinv, hA);
    // layer 3
    k_gemm128<<<(NN + 63) / 64, 256, 0, stream>>>(hA, W3, hB);
    k_agg128 <<<NN / 4, 256, 0, stream>>>(hB, b3, row_ptr, e_src, dinv, hA);
    // head
    k_cls<<<(NN + 15) / 16, 256, 0, stream>>>(hA, Wc1, bc1, Wc2, bc2, outp);
}

// Round 5
// 380.888 us; speedup vs baseline: 2.0295x; 1.0061x over previous
//
#include <hip/hip_runtime.h>
#include <math.h>

#define NN 50000
#define EE 640000
#define IND 23
#define HID 128
#define MIDD 64
#define NCLS 12
#define NB 49          // ceil(NN / 1024) scan chunks

// ---- graph build ----------------------------------------------------------

__global__ void k_count(const int* __restrict__ dst, int* __restrict__ cnt, int e) {
    int i = blockIdx.x * blockDim.x + threadIdx.x;
    if (i < e) atomicAdd(&cnt[dst[i]], 1);
}

__global__ __launch_bounds__(256) void k_scan_local(const int* __restrict__ cnt,
                                                    int* __restrict__ row_ptr,
                                                    float* __restrict__ dinv,
                                                    int* __restrict__ sums) {
    __shared__ int wtot[4];
    const int tid = threadIdx.x;
    const int wid = tid >> 6, lane = tid & 63;
    const int base = blockIdx.x * 1024 + tid * 4;
    int v[4];
#pragma unroll
    for (int t = 0; t < 4; ++t) {
        int i = base + t;
        v[t] = (i < NN) ? cnt[i] : 0;
        if (i < NN) dinv[i] = rsqrtf((float)v[t] + 1.0f);  // +1 self loop
    }
    int slocal = v[0] + v[1] + v[2] + v[3];
    int val = slocal;
#pragma unroll
    for (int off = 1; off < 64; off <<= 1) {
        int t = __shfl_up(val, off, 64);
        if (lane >= off) val += t;
    }
    if (lane == 63) wtot[wid] = val;
    __syncthreads();
    int woff = 0;
#pragma unroll
    for (int w = 0; w < 4; ++w) woff += (w < wid) ? wtot[w] : 0;
    int run = woff + val - slocal;
#pragma unroll
    for (int t = 0; t < 4; ++t) {
        int i = base + t;
        if (i < NN) row_ptr[i] = run;
        run += v[t];
    }
    if (tid == 255) sums[blockIdx.x] = woff + val;
}

__global__ void k_scan_sums(const int* __restrict__ sums, int* __restrict__ offs,
                            int* __restrict__ row_ptr) {
    const int lane = threadIdx.x;
    int v = (lane < NB) ? sums[lane] : 0;
    int val = v;
#pragma unroll
    for (int off = 1; off < 64; off <<= 1) {
        int t = __shfl_up(val, off, 64);
        if (lane >= off) val += t;
    }
    if (lane < NB) offs[lane] = val - v;
    if (lane == NB - 1) row_ptr[NN] = val;
}

__global__ __launch_bounds__(256) void k_scan_apply(int* __restrict__ row_ptr,
                                                    const int* __restrict__ offs,
                                                    int* __restrict__ cursor) {
    const int base = blockIdx.x * 1024 + threadIdx.x * 4;
    const int o = offs[blockIdx.x];
#pragma unroll
    for (int t = 0; t < 4; ++t) {
        int i = base + t;
        if (i < NN) {
            int rp = row_ptr[i] + o;
            row_ptr[i] = rp;
            cursor[i] = rp;
        }
    }
}

__global__ void k_fill(const int* __restrict__ src, const int* __restrict__ dst,
                       int* __restrict__ cursor, int* __restrict__ e_src, int e) {
    int i = blockIdx.x * blockDim.x + threadIdx.x;
    if (i < e) {
        int d = dst[i];
        int pos = atomicAdd(&cursor[d], 1);
        e_src[pos] = src[i];
    }
}

// pad x rows 23 -> 32 floats, pre-scaled by dinv[node] (rank-1 norm trick)
__global__ __launch_bounds__(256) void k_pad(const float* __restrict__ x,
                                             const float* __restrict__ dinv,
                                             float* __restrict__ xp) {
    int i = blockIdx.x * 256 + threadIdx.x;   // over NN*32
    int node = i >> 5, f = i & 31;
    xp[i] = (f < IND) ? x[node * IND + f] * dinv[node] : 0.f;
}

// ---- layer 1 fused: h1 = tanh( (A @ x) @ W1 + b1 ) ------------------------
// wave per node. xp rows are pre-scaled by dinv[src]; aggregation is a pure
// sum, final scale by dinv[i] (rank-1 factorization of the edge norm).
__global__ __launch_bounds__(256) void k_l1(const float* __restrict__ xp,
                                            const float* __restrict__ W1,
                                            const float* __restrict__ b1,
                                            const int* __restrict__ row_ptr,
                                            const int* __restrict__ e_src,
                                            const float* __restrict__ dinv,
                                            float* __restrict__ out) {
    const int tid = threadIdx.x;
    const int i = blockIdx.x * 4 + (tid >> 6);
    const int lane = tid & 63;
    const int slot = lane >> 5;     // edge slot 0/1
    const int f = lane & 31;        // feature lane (23 live, 9 padded zeros)
    const int beg = row_ptr[i];
    const int deg = row_ptr[i + 1] - beg;
    float acc = 0.f;
    for (int base = 0; base < deg; base += 64) {
        const int cnt = min(64, deg - base);
        int s_l = 0;
        if (lane < cnt) s_l = e_src[beg + base + lane];
        int e = 0;
#pragma unroll 4
        for (; e + 1 < cnt; e += 2) {
            int s = __shfl(s_l, e + slot, 64);
            acc += xp[s * 32 + f];
        }
        if (e < cnt) {
            int s = __shfl(s_l, e, 64);
            if (slot == 0) acc += xp[s * 32 + f];
        }
    }
    acc += __shfl_down(acc, 32, 64);                 // fold slot 1 -> lanes 0..31
    const float di = dinv[i];
    if (lane < 32) acc = (acc + xp[i * 32 + lane]) * di;  // self + final scale
    // phase 2: broadcast xagg[0..22] from lanes 0..22
    float a0 = b1[lane], a1 = b1[lane + 64];
#pragma unroll
    for (int k = 0; k < IND; ++k) {
        float xk = __shfl(acc, k, 64);
        a0 += xk * W1[k * HID + lane];
        a1 += xk * W1[k * HID + lane + 64];
    }
    out[i * HID + lane]      = tanhf(a0);
    out[i * HID + lane + 64] = tanhf(a1);
}

// ---- tiled 128x128 GEMM:  out[row] = (hin @ W)[row] * dinv[row] -----------

__global__ __launch_bounds__(256) void k_gemm128(const float* __restrict__ hin,
                                                 const float* __restrict__ W,
                                                 const float* __restrict__ dinv,
                                                 float* __restrict__ out) {
    __shared__ float Hs[64 * 36];
    __shared__ float Ws[32 * 128];
    const int tid = threadIdx.x;
    const int b0 = blockIdx.x * 64;
    const int ng = tid >> 4;
    const int cg = tid & 15;
    const float4* hin4 = (const float4*)hin;
    const float4* W4 = (const float4*)W;

    float acc[4][8];
#pragma unroll
    for (int m = 0; m < 4; ++m)
#pragma unroll
        for (int c = 0; c < 8; ++c) acc[m][c] = 0.f;

    for (int ks = 0; ks < HID; ks += 32) {
#pragma unroll
        for (int t = 0; t < 2; ++t) {
            int id = t * 256 + tid;
            int row = id >> 3;
            int k4 = id & 7;
            int node = b0 + row;
            float4 v = make_float4(0.f, 0.f, 0.f, 0.f);
            if (node < NN) v = hin4[node * 32 + (ks >> 2) + k4];
            *(float4*)&Hs[row * 36 + k4 * 4] = v;
        }
#pragma unroll
        for (int t = 0; t < 4; ++t) {
            int id = t * 256 + tid;
            int row = id >> 5;
            int c4 = id & 31;
            *(float4*)&Ws[row * 128 + c4 * 4] = W4[(ks + row) * 32 + c4];
        }
        __syncthreads();
#pragma unroll 8
        for (int kk = 0; kk < 32; ++kk) {
            float4 w0 = *(float4*)&Ws[kk * 128 + cg * 8];
            float4 w1 = *(float4*)&Ws[kk * 128 + cg * 8 + 4];
#pragma unroll
            for (int m = 0; m < 4; ++m) {
                float hv = Hs[(ng * 4 + m) * 36 + kk];
                acc[m][0] += hv * w0.x; acc[m][1] += hv * w0.y;
                acc[m][2] += hv * w0.z; acc[m][3] += hv * w0.w;
                acc[m][4] += hv * w1.x; acc[m][5] += hv * w1.y;
                acc[m][6] += hv * w1.z; acc[m][7] += hv * w1.w;
            }
        }
        __syncthreads();
    }
    float4* out4 = (float4*)out;
#pragma unroll
    for (int m = 0; m < 4; ++m) {
        int node = b0 + ng * 4 + m;
        if (node < NN) {
            float dv = dinv[node];
            out4[node * 32 + cg * 2]     = make_float4(acc[m][0] * dv, acc[m][1] * dv,
                                                       acc[m][2] * dv, acc[m][3] * dv);
            out4[node * 32 + cg * 2 + 1] = make_float4(acc[m][4] * dv, acc[m][5] * dv,
                                                       acc[m][6] * dv, acc[m][7] * dv);
        }
    }
}

// ---- 128-dim aggregation: rows pre-scaled, pure-sum gather ----------------

__global__ __launch_bounds__(256) void k_agg128(const float* __restrict__ hlin,
                                                const float* __restrict__ b,
                                                const int* __restrict__ row_ptr,
                                                const int* __restrict__ e_src,
                                                const float* __restrict__ dinv,
                                                float* __restrict__ out) {
    const int tid = threadIdx.x;
    const int i = blockIdx.x * 4 + (tid >> 6);
    const int lane = tid & 63;
    const int slot = lane >> 5;
    const int f4 = lane & 31;
    const float4* h4 = (const float4*)hlin;
    const int beg = row_ptr[i];
    const int deg = row_ptr[i + 1] - beg;
    float4 acc = make_float4(0.f, 0.f, 0.f, 0.f);
    for (int base = 0; base < deg; base += 64) {
        const int cnt = min(64, deg - base);
        int s_l = 0;
        if (lane < cnt) s_l = e_src[beg + base + lane];
        int e = 0;
#pragma unroll 4
        for (; e + 1 < cnt; e += 2) {
            int s = __shfl(s_l, e + slot, 64);
            float4 v = h4[s * 32 + f4];
            acc.x += v.x; acc.y += v.y; acc.z += v.z; acc.w += v.w;
        }
        if (e < cnt) {
            int s = __shfl(s_l, e, 64);
            if (slot == 0) {
                float4 v = h4[s * 32 + f4];
                acc.x += v.x; acc.y += v.y; acc.z += v.z; acc.w += v.w;
            }
        }
    }
    acc.x += __shfl_down(acc.x, 32, 64);
    acc.y += __shfl_down(acc.y, 32, 64);
    acc.z += __shfl_down(acc.z, 32, 64);
    acc.w += __shfl_down(acc.w, 32, 64);
    if (lane < 32) {
        const float di = dinv[i];
        float4 v = h4[i * 32 + lane];          // self row (pre-scaled)
        float4 bb = ((const float4*)b)[lane];
        float4 s;
        s.x = tanhf(bb.x + (acc.x + v.x) * di);
        s.y = tanhf(bb.y + (acc.y + v.y) * di);
        s.z = tanhf(bb.z + (acc.z + v.z) * di);
        s.w = tanhf(bb.w + (acc.w + v.w) * di);
        ((float4*)out)[i * 32 + lane] = s;
    }
}

// ---- classifier head: 16 nodes/block, 128 -> 64 -> 12 ---------------------

__global__ __launch_bounds__(256) void k_cls(const float* __restrict__ h,
                                             const float* __restrict__ Wc1,
                                             const float* __restrict__ bc1,
                                             const float* __restrict__ Wc2,
                                             const float* __restrict__ bc2,
                                             float* __restrict__ out) {
    __shared__ float hs[16 * 128];
    __shared__ float ms[16 * 65];
    const int tid = threadIdx.x;
    const int b0 = blockIdx.x * 16;
    const float4* h4 = (const float4*)h;
#pragma unroll
    for (int t = 0; t < 2; ++t) {
        int id = t * 256 + tid;
        int node = id >> 5;
        int k4 = id & 31;
        float4 v = make_float4(0.f, 0.f, 0.f, 0.f);
        if (b0 + node < NN) v = h4[(b0 + node) * 32 + k4];
        *(float4*)&hs[node * 128 + k4 * 4] = v;
    }
    __syncthreads();
    const int q = tid >> 6;
    const int c = tid & 63;
    float acc[4];
#pragma unroll
    for (int t = 0; t < 4; ++t) acc[t] = 0.f;
    for (int k = 0; k < HID; ++k) {
        float w = Wc1[k * MIDD + c];
#pragma unroll
        for (int t = 0; t < 4; ++t) acc[t] += hs[(q + 4 * t) * 128 + k] * w;
    }
    float bb = bc1[c];
#pragma unroll
    for (int t = 0; t < 4; ++t) ms[(q + 4 * t) * 65 + c] = acc[t] + bb;
    __syncthreads();
    if (tid < 16 * NCLS) {
        int m = tid / NCLS;
        int cls = tid % NCLS;
        int node = b0 + m;
        if (node < NN) {
            float o = bc2[cls];
#pragma unroll 8
            for (int k = 0; k < MIDD; ++k) o += ms[m * 65 + k] * Wc2[k * NCLS + cls];
            out[node * NCLS + cls] = o;
        }
    }
}

// ---- launch ---------------------------------------------------------------

extern "C" void kernel_launch(void* const* d_in, const int* in_sizes, int n_in,
                              void* d_out, int out_size, void* d_ws, size_t ws_size,
                              hipStream_t stream) {
    const float* x    = (const float*)d_in[0];
    const int*   edge = (const int*)d_in[1];
    const int*   src  = edge;
    const int*   dst  = edge + EE;
    const float* W1  = (const float*)d_in[2];  const float* b1  = (const float*)d_in[3];
    const float* W2  = (const float*)d_in[4];  const float* b2  = (const float*)d_in[5];
    const float* W3  = (const float*)d_in[6];  const float* b3  = (const float*)d_in[7];
    const float* Wc1 = (const float*)d_in[8];  const float* bc1 = (const float*)d_in[9];
    const float* Wc2 = (const float*)d_in[10]; const float* bc2 = (const float*)d_in[11];
    float* outp = (float*)d_out;

    char* p = (char*)d_ws;
    int*   cnt     = (int*)p;   p += 200064;          // NN ints, padded
    int*   row_ptr = (int*)p;   p += 200064;          // NN+1 ints, padded
    float* dinv    = (float*)p; p += 200064;
    int*   sums    = (int*)p;   p += 256;
    int*   offs    = (int*)p;   p += 256;
    int*   e_src   = (int*)p;   p += (size_t)EE * 4;
    float* hA      = (float*)p; p += (size_t)NN * HID * 4;
    float* hB      = (float*)p; p += (size_t)NN * HID * 4;
    float* xp      = hB;   // alias: hB not live until layer-2 gemm; xp dead by then

    // graph build
    hipMemsetAsync(cnt, 0, (size_t)NN * 4, stream);
    k_count     <<<(EE + 255) / 256, 256, 0, stream>>>(dst, cnt, EE);
    k_scan_local<<<NB, 256, 0, stream>>>(cnt, row_ptr, dinv, sums);
    k_scan_sums <<<1, 64, 0, stream>>>(sums, offs, row_ptr);
    k_scan_apply<<<NB, 256, 0, stream>>>(row_ptr, offs, cnt);   // cnt becomes cursor
    k_fill      <<<(EE + 255) / 256, 256, 0, stream>>>(src, dst, cnt, e_src, EE);
    k_pad       <<<(NN * 32) / 256, 256, 0, stream>>>(x, dinv, xp);

    // layer 1 (fused (A@X)@W1)
    k_l1     <<<NN / 4, 256, 0, stream>>>(xp, W1, b1, row_ptr, e_src, dinv, hA);
    // layer 2
    k_gemm128<<<(NN + 63) / 64, 256, 0, stream>>>(hA, W2, dinv, hB);
    k_agg128 <<<NN / 4, 256, 0, stream>>>(hB, b2, row_ptr, e_src, dinv, hA);
    // layer 3
    k_gemm128<<<(NN + 63) / 64, 256, 0, stream>>>(hA, W3, dinv, hB);
    k_agg128 <<<NN / 4, 256, 0, stream>>>(hB, b3, row_ptr, e_src, dinv, hA);
    // head
    k_cls<<<(NN + 15) / 16, 256, 0, stream>>>(hA, Wc1, bc1, Wc2, bc2, outp);
}

// Round 8
// 342.469 us; speedup vs baseline: 2.2572x; 1.1122x over previous
//
#include <hip/hip_runtime.h>
#include <math.h>

#define NN 50000
#define EE 640000
#define IND 23
#define HID 128
#define MIDD 64
#define NCLS 12
#define NB 49          // ceil(NN / 1024) scan chunks
#define QS 32766.0f
#define INVQS (1.0f / 32766.0f)

typedef short short8v __attribute__((ext_vector_type(8)));

// ---- graph build ----------------------------------------------------------

__global__ void k_count(const int* __restrict__ dst, int* __restrict__ cnt, int e) {
    int i = blockIdx.x * blockDim.x + threadIdx.x;
    if (i < e) atomicAdd(&cnt[dst[i]], 1);
}

__global__ __launch_bounds__(256) void k_scan_local(const int* __restrict__ cnt,
                                                    int* __restrict__ row_ptr,
                                                    float* __restrict__ dinv,
                                                    int* __restrict__ sums) {
    __shared__ int wtot[4];
    const int tid = threadIdx.x;
    const int wid = tid >> 6, lane = tid & 63;
    const int base = blockIdx.x * 1024 + tid * 4;
    int v[4];
#pragma unroll
    for (int t = 0; t < 4; ++t) {
        int i = base + t;
        v[t] = (i < NN) ? cnt[i] : 0;
        if (i < NN) dinv[i] = rsqrtf((float)v[t] + 1.0f);  // +1 self loop
    }
    int slocal = v[0] + v[1] + v[2] + v[3];
    int val = slocal;
#pragma unroll
    for (int off = 1; off < 64; off <<= 1) {
        int t = __shfl_up(val, off, 64);
        if (lane >= off) val += t;
    }
    if (lane == 63) wtot[wid] = val;
    __syncthreads();
    int woff = 0;
#pragma unroll
    for (int w = 0; w < 4; ++w) woff += (w < wid) ? wtot[w] : 0;
    int run = woff + val - slocal;
#pragma unroll
    for (int t = 0; t < 4; ++t) {
        int i = base + t;
        if (i < NN) row_ptr[i] = run;
        run += v[t];
    }
    if (tid == 255) sums[blockIdx.x] = woff + val;
}

__global__ void k_scan_sums(const int* __restrict__ sums, int* __restrict__ offs,
                            int* __restrict__ row_ptr) {
    const int lane = threadIdx.x;
    int v = (lane < NB) ? sums[lane] : 0;
    int val = v;
#pragma unroll
    for (int off = 1; off < 64; off <<= 1) {
        int t = __shfl_up(val, off, 64);
        if (lane >= off) val += t;
    }
    if (lane < NB) offs[lane] = val - v;
    if (lane == NB - 1) row_ptr[NN] = val;
}

__global__ __launch_bounds__(256) void k_scan_apply(int* __restrict__ row_ptr,
                                                    const int* __restrict__ offs,
                                                    int* __restrict__ cursor) {
    const int base = blockIdx.x * 1024 + threadIdx.x * 4;
    const int o = offs[blockIdx.x];
#pragma unroll
    for (int t = 0; t < 4; ++t) {
        int i = base + t;
        if (i < NN) {
            int rp = row_ptr[i] + o;
            row_ptr[i] = rp;
            cursor[i] = rp;
        }
    }
}

__global__ void k_fill(const int* __restrict__ src, const int* __restrict__ dst,
                       int* __restrict__ cursor, int* __restrict__ e_src, int e) {
    int i = blockIdx.x * blockDim.x + threadIdx.x;
    if (i < e) {
        int d = dst[i];
        int pos = atomicAdd(&cursor[d], 1);
        e_src[pos] = src[i];
    }
}

// pad x rows 23 -> 32 floats, pre-scaled by dinv[node] (rank-1 norm fold)
__global__ __launch_bounds__(256) void k_pad(const float* __restrict__ x,
                                             const float* __restrict__ dinv,
                                             float* __restrict__ xp) {
    int i = blockIdx.x * 256 + threadIdx.x;   // over NN*32
    int node = i >> 5, f = i & 31;
    xp[i] = (f < IND) ? x[node * IND + f] * dinv[node] : 0.f;
}

// ---- layer 1 fused: q1 = quant( tanh( (A @ x) @ W1 + b1 ) ) ---------------
// wave per node; 8 edges in flight. NOTE: remainder shfl must run under a
// WAVE-UNIFORM condition — ds_bpermute from an EXEC-masked source lane is
// undefined (this was the round-6/7 correctness bug).
__global__ __launch_bounds__(256) void k_l1(const float* __restrict__ xp,
                                            const float* __restrict__ W1,
                                            const float* __restrict__ b1,
                                            const int* __restrict__ row_ptr,
                                            const int* __restrict__ e_src,
                                            const float* __restrict__ dinv,
                                            short* __restrict__ outq) {
    const int tid = threadIdx.x;
    const int i = blockIdx.x * 4 + (tid >> 6);
    const int lane = tid & 63;
    const int slot = lane >> 3;     // 8 edge slots
    const int f = lane & 7;         // float4 index within 32-float row
    const float4* xp4 = (const float4*)xp;
    const int beg = row_ptr[i];
    const int deg = row_ptr[i + 1] - beg;
    float4 acc = make_float4(0.f, 0.f, 0.f, 0.f);
    for (int base = 0; base < deg; base += 64) {
        const int cnt = min(64, deg - base);
        int s_l = 0;
        if (lane < cnt) s_l = e_src[beg + base + lane];
        int e = 0;
        for (; e + 8 <= cnt; e += 8) {          // uniform: all source lanes active
            int s = __shfl(s_l, e + slot, 64);
            float4 v = xp4[s * 8 + f];
            acc.x += v.x; acc.y += v.y; acc.z += v.z; acc.w += v.w;
        }
        if (e < cnt) {                          // WAVE-UNIFORM: all lanes in shfl
            int s = __shfl(s_l, e + slot, 64);  // tail lanes read s_l=0 (unused)
            if (e + slot < cnt) {
                float4 v = xp4[s * 8 + f];
                acc.x += v.x; acc.y += v.y; acc.z += v.z; acc.w += v.w;
            }
        }
    }
    // fold 8 slots -> lanes 0..7
#pragma unroll
    for (int off = 32; off >= 8; off >>= 1) {
        acc.x += __shfl_down(acc.x, off, 64);
        acc.y += __shfl_down(acc.y, off, 64);
        acc.z += __shfl_down(acc.z, off, 64);
        acc.w += __shfl_down(acc.w, off, 64);
    }
    const float di = dinv[i];
    if (lane < 8) {
        float4 v = xp4[i * 8 + lane];   // self row (pre-folded)
        acc.x = (acc.x + v.x) * di; acc.y = (acc.y + v.y) * di;
        acc.z = (acc.z + v.z) * di; acc.w = (acc.w + v.w) * di;
    }
    // broadcast xagg[0..22] from lanes 0..5 (float4 components)
    float a0 = b1[lane], a1 = b1[lane + 64];
#pragma unroll
    for (int k = 0; k < IND; ++k) {
        float comp = ((k & 3) == 0) ? acc.x : ((k & 3) == 1) ? acc.y
                   : ((k & 3) == 2) ? acc.z : acc.w;
        float xk = __shfl(comp, k >> 2, 64);
        a0 += xk * W1[k * HID + lane];
        a1 += xk * W1[k * HID + lane + 64];
    }
    outq[i * HID + lane]      = (short)__float2int_rn(tanhf(a0) * QS);
    outq[i * HID + lane + 64] = (short)__float2int_rn(tanhf(a1) * QS);
}

// ---- aggregation over int16 tanh rows -------------------------------------
// aggf_i = dinv_i * ( sum_s dinv_s*q_s + dinv_i*q_i ) / QS
// wave per node; 4 edge slots x 16 short8-lanes (16B) = 256B row.
__global__ __launch_bounds__(256) void k_aggq(const short* __restrict__ hq,
                                              const int* __restrict__ row_ptr,
                                              const int* __restrict__ e_src,
                                              const float* __restrict__ dinv,
                                              float* __restrict__ aggf) {
    const int tid = threadIdx.x;
    const int i = blockIdx.x * 4 + (tid >> 6);
    const int lane = tid & 63;
    const int slot = lane >> 4;     // 4 edge slots
    const int f = lane & 15;        // short8 index within 128-short row
    const short8v* h8 = (const short8v*)hq;
    const int beg = row_ptr[i];
    const int deg = row_ptr[i + 1] - beg;
    float facc[8];
#pragma unroll
    for (int t = 0; t < 8; ++t) facc[t] = 0.f;
    for (int base = 0; base < deg; base += 64) {
        const int cnt = min(64, deg - base);
        int s_l = 0; float n_l = 0.f;
        if (lane < cnt) {
            s_l = e_src[beg + base + lane];
            n_l = dinv[s_l];
        }
        int e = 0;
#pragma unroll 2
        for (; e + 4 <= cnt; e += 4) {          // uniform: all source lanes active
            int s = __shfl(s_l, e + slot, 64);
            float nr = __shfl(n_l, e + slot, 64);
            short8v v = h8[s * 16 + f];
#pragma unroll
            for (int t = 0; t < 8; ++t) facc[t] += (float)v[t] * nr;
        }
        if (e < cnt) {                          // WAVE-UNIFORM: all lanes in shfl
            int s = __shfl(s_l, e + slot, 64);
            float nr = __shfl(n_l, e + slot, 64);
            if (e + slot < cnt) {
                short8v v = h8[s * 16 + f];
#pragma unroll
                for (int t = 0; t < 8; ++t) facc[t] += (float)v[t] * nr;
            }
        }
    }
    // fold 4 slots -> lanes 0..15
#pragma unroll
    for (int off = 32; off >= 16; off >>= 1)
#pragma unroll
        for (int t = 0; t < 8; ++t) facc[t] += __shfl_down(facc[t], off, 64);
    if (lane < 16) {
        const float di = dinv[i];
        const float sc = di * INVQS;
        short8v v = h8[i * 16 + lane];          // self row
        float4 o0, o1;
        o0.x = (facc[0] + di * (float)v[0]) * sc;
        o0.y = (facc[1] + di * (float)v[1]) * sc;
        o0.z = (facc[2] + di * (float)v[2]) * sc;
        o0.w = (facc[3] + di * (float)v[3]) * sc;
        o1.x = (facc[4] + di * (float)v[4]) * sc;
        o1.y = (facc[5] + di * (float)v[5]) * sc;
        o1.z = (facc[6] + di * (float)v[6]) * sc;
        o1.w = (facc[7] + di * (float)v[7]) * sc;
        ((float4*)aggf)[i * 32 + lane * 2]     = o0;
        ((float4*)aggf)[i * 32 + lane * 2 + 1] = o1;
    }
}

// ---- tiled 128x128 GEMM with tanh epilogue --------------------------------
// out = tanh(hin @ W + b); qout: int16 quantized; fout: fp32 (in-place safe:
// each block reads only its own 64 rows of hin before writing them).
__global__ __launch_bounds__(256) void k_gemmT(const float* __restrict__ hin,
                                               const float* __restrict__ W,
                                               const float* __restrict__ bias,
                                               short* __restrict__ qout,
                                               float* __restrict__ fout) {
    __shared__ float Hs[64 * 36];
    __shared__ float Ws[32 * 128];
    const int tid = threadIdx.x;
    const int b0 = blockIdx.x * 64;
    const int ng = tid >> 4;
    const int cg = tid & 15;
    const float4* hin4 = (const float4*)hin;
    const float4* W4 = (const float4*)W;

    float acc[4][8];
#pragma unroll
    for (int m = 0; m < 4; ++m)
#pragma unroll
        for (int c = 0; c < 8; ++c) acc[m][c] = 0.f;

    for (int ks = 0; ks < HID; ks += 32) {
#pragma unroll
        for (int t = 0; t < 2; ++t) {
            int id = t * 256 + tid;
            int row = id >> 3;
            int k4 = id & 7;
            int node = b0 + row;
            float4 v = make_float4(0.f, 0.f, 0.f, 0.f);
            if (node < NN) v = hin4[node * 32 + (ks >> 2) + k4];
            *(float4*)&Hs[row * 36 + k4 * 4] = v;
        }
#pragma unroll
        for (int t = 0; t < 4; ++t) {
            int id = t * 256 + tid;
            int row = id >> 5;
            int c4 = id & 31;
            *(float4*)&Ws[row * 128 + c4 * 4] = W4[(ks + row) * 32 + c4];
        }
        __syncthreads();
#pragma unroll 8
        for (int kk = 0; kk < 32; ++kk) {
            float4 w0 = *(float4*)&Ws[kk * 128 + cg * 8];
            float4 w1 = *(float4*)&Ws[kk * 128 + cg * 8 + 4];
#pragma unroll
            for (int m = 0; m < 4; ++m) {
                float hv = Hs[(ng * 4 + m) * 36 + kk];
                acc[m][0] += hv * w0.x; acc[m][1] += hv * w0.y;
                acc[m][2] += hv * w0.z; acc[m][3] += hv * w0.w;
                acc[m][4] += hv * w1.x; acc[m][5] += hv * w1.y;
                acc[m][6] += hv * w1.z; acc[m][7] += hv * w1.w;
            }
        }
        __syncthreads();
    }
    const float4* b4 = (const float4*)bias;
    float4 bb0 = b4[cg * 2], bb1 = b4[cg * 2 + 1];
#pragma unroll
    for (int m = 0; m < 4; ++m) {
        int node = b0 + ng * 4 + m;
        if (node < NN) {
            float t0 = tanhf(acc[m][0] + bb0.x);
            float t1 = tanhf(acc[m][1] + bb0.y);
            float t2 = tanhf(acc[m][2] + bb0.z);
            float t3 = tanhf(acc[m][3] + bb0.w);
            float t4 = tanhf(acc[m][4] + bb1.x);
            float t5 = tanhf(acc[m][5] + bb1.y);
            float t6 = tanhf(acc[m][6] + bb1.z);
            float t7 = tanhf(acc[m][7] + bb1.w);
            if (qout) {
                short8v qv;
                qv[0] = (short)__float2int_rn(t0 * QS);
                qv[1] = (short)__float2int_rn(t1 * QS);
                qv[2] = (short)__float2int_rn(t2 * QS);
                qv[3] = (short)__float2int_rn(t3 * QS);
                qv[4] = (short)__float2int_rn(t4 * QS);
                qv[5] = (short)__float2int_rn(t5 * QS);
                qv[6] = (short)__float2int_rn(t6 * QS);
                qv[7] = (short)__float2int_rn(t7 * QS);
                ((short8v*)qout)[node * 16 + cg] = qv;
            }
            if (fout) {
                ((float4*)fout)[node * 32 + cg * 2]     = make_float4(t0, t1, t2, t3);
                ((float4*)fout)[node * 32 + cg * 2 + 1] = make_float4(t4, t5, t6, t7);
            }
        }
    }
}

// ---- classifier head: 16 nodes/block, 128 -> 64 -> 12 ---------------------

__global__ __launch_bounds__(256) void k_cls(const float* __restrict__ h,
                                             const float* __restrict__ Wc1,
                                             const float* __restrict__ bc1,
                                             const float* __restrict__ Wc2,
                                             const float* __restrict__ bc2,
                                             float* __restrict__ out) {
    __shared__ float hs[16 * 128];
    __shared__ float ms[16 * 65];
    const int tid = threadIdx.x;
    const int b0 = blockIdx.x * 16;
    const float4* h4 = (const float4*)h;
#pragma unroll
    for (int t = 0; t < 2; ++t) {
        int id = t * 256 + tid;
        int node = id >> 5;
        int k4 = id & 31;
        float4 v = make_float4(0.f, 0.f, 0.f, 0.f);
        if (b0 + node < NN) v = h4[(b0 + node) * 32 + k4];
        *(float4*)&hs[node * 128 + k4 * 4] = v;
    }
    __syncthreads();
    const int q = tid >> 6;
    const int c = tid & 63;
    float acc[4];
#pragma unroll
    for (int t = 0; t < 4; ++t) acc[t] = 0.f;
    for (int k = 0; k < HID; ++k) {
        float w = Wc1[k * MIDD + c];
#pragma unroll
        for (int t = 0; t < 4; ++t) acc[t] += hs[(q + 4 * t) * 128 + k] * w;
    }
    float bb = bc1[c];
#pragma unroll
    for (int t = 0; t < 4; ++t) ms[(q + 4 * t) * 65 + c] = acc[t] + bb;
    __syncthreads();
    if (tid < 16 * NCLS) {
        int m = tid / NCLS;
        int cls = tid % NCLS;
        int node = b0 + m;
        if (node < NN) {
            float o = bc2[cls];
#pragma unroll 8
            for (int k = 0; k < MIDD; ++k) o += ms[m * 65 + k] * Wc2[k * NCLS + cls];
            out[node * NCLS + cls] = o;
        }
    }
}

// ---- launch ---------------------------------------------------------------

extern "C" void kernel_launch(void* const* d_in, const int* in_sizes, int n_in,
                              void* d_out, int out_size, void* d_ws, size_t ws_size,
                              hipStream_t stream) {
    const float* x    = (const float*)d_in[0];
    const int*   edge = (const int*)d_in[1];
    const int*   src  = edge;
    const int*   dst  = edge + EE;
    const float* W1  = (const float*)d_in[2];  const float* b1  = (const float*)d_in[3];
    const float* W2  = (const float*)d_in[4];  const float* b2  = (const float*)d_in[5];
    const float* W3  = (const float*)d_in[6];  const float* b3  = (const float*)d_in[7];
    const float* Wc1 = (const float*)d_in[8];  const float* bc1 = (const float*)d_in[9];
    const float* Wc2 = (const float*)d_in[10]; const float* bc2 = (const float*)d_in[11];
    float* outp = (float*)d_out;

    char* p = (char*)d_ws;
    int*   cnt     = (int*)p;   p += 200064;          // NN ints, padded
    int*   row_ptr = (int*)p;   p += 200064;          // NN+1 ints, padded
    float* dinv    = (float*)p; p += 200064;
    int*   sums    = (int*)p;   p += 256;
    int*   offs    = (int*)p;   p += 256;
    int*   e_src   = (int*)p;   p += (size_t)EE * 4;
    float* xp      = (float*)p; p += (size_t)NN * 32 * 4;    // padded pre-folded x
    short* q       = (short*)p; p += (size_t)NN * HID * 2;   // int16 tanh (q1/q2 alias)
    float* aggf    = (float*)p; p += (size_t)NN * HID * 4;   // fp32 agg / h3 (in-place)

    // graph build
    hipMemsetAsync(cnt, 0, (size_t)NN * 4, stream);
    k_count     <<<(EE + 255) / 256, 256, 0, stream>>>(dst, cnt, EE);
    k_scan_local<<<NB, 256, 0, stream>>>(cnt, row_ptr, dinv, sums);
    k_scan_sums <<<1, 64, 0, stream>>>(sums, offs, row_ptr);
    k_scan_apply<<<NB, 256, 0, stream>>>(row_ptr, offs, cnt);   // cnt becomes cursor
    k_fill      <<<(EE + 255) / 256, 256, 0, stream>>>(src, dst, cnt, e_src, EE);
    k_pad       <<<(NN * 32) / 256, 256, 0, stream>>>(x, dinv, xp);

    // layer 1: q1 = quant(tanh((A@x)@W1 + b1))
    k_l1  <<<NN / 4, 256, 0, stream>>>(xp, W1, b1, row_ptr, e_src, dinv, q);
    // layer 2: agg(q1) -> gemm+tanh -> q2   (q2 aliases q1; stream-ordered)
    k_aggq <<<NN / 4, 256, 0, stream>>>(q, row_ptr, e_src, dinv, aggf);
    k_gemmT<<<(NN + 63) / 64, 256, 0, stream>>>(aggf, W2, b2, q, nullptr);
    // layer 3: agg(q2) -> gemm+tanh -> h3 fp32 (in-place over aggf)
    k_aggq <<<NN / 4, 256, 0, stream>>>(q, row_ptr, e_src, dinv, aggf);
    k_gemmT<<<(NN + 63) / 64, 256, 0, stream>>>(aggf, W3, b3, nullptr, aggf);
    // head
    k_cls<<<(NN + 15) / 16, 256, 0, stream>>>(aggf, Wc1, bc1, Wc2, bc2, outp);
}